// Round 1
// baseline (2122.911 us; speedup 1.0000x reference)
//
#include <hip/hip_runtime.h>
#include <hip/hip_bf16.h>

typedef unsigned short u16;
typedef __bf16 bf16x8 __attribute__((ext_vector_type(8)));
typedef float f32x4 __attribute__((ext_vector_type(4)));

__device__ __forceinline__ u16 f2bf(float v) {
    __hip_bfloat16 h = __float2bfloat16(v);
    return __builtin_bit_cast(u16, h);
}

// async global -> LDS, 16B per lane. LDS dst must be wave-uniform-base + lane*16.
__device__ __forceinline__ void gld_lds16(const u16* g, u16* l) {
    __builtin_amdgcn_global_load_lds(
        (const __attribute__((address_space(1))) unsigned int*)(const void*)g,
        (__attribute__((address_space(3))) unsigned int*)(void*)l, 16, 0, 0);
}

// ---------------- elementwise / transform kernels ----------------

__global__ void k_convert_bf16(const float* __restrict__ s, u16* __restrict__ d, long n) {
    long i = ((long)blockIdx.x * 256 + threadIdx.x) * 4;
    if (i < n) {
        float4 v = *(const float4*)(s + i);
        u16 a = f2bf(v.x), b = f2bf(v.y), c = f2bf(v.z), e = f2bf(v.w);
        ushort4 o; o.x = a; o.y = b; o.z = c; o.w = e;
        *(ushort4*)(d + i) = o;
    }
}

// dst[c][r] = bf16(src[r][c]); grid (C/32, R/32), block 256
__global__ void k_transpose_f32_bf16(const float* __restrict__ src, u16* __restrict__ dst,
                                     int R, int C, int ld_src, int ld_dst) {
    __shared__ u16 t[32][33];
    int c0 = blockIdx.x * 32, r0 = blockIdx.y * 32;
    int tx = threadIdx.x & 31, ty = threadIdx.x >> 5; // ty 0..7
#pragma unroll
    for (int i = 0; i < 32; i += 8)
        t[ty + i][tx] = f2bf(src[(size_t)(r0 + ty + i) * ld_src + c0 + tx]);
    __syncthreads();
#pragma unroll
    for (int i = 0; i < 32; i += 8)
        dst[(size_t)(c0 + ty + i) * ld_dst + r0 + tx] = t[tx][ty + i];
}

__global__ void k_transpose_u16(const u16* __restrict__ src, u16* __restrict__ dst,
                                int R, int C, int ld_src, int ld_dst) {
    __shared__ u16 t[32][33];
    int c0 = blockIdx.x * 32, r0 = blockIdx.y * 32;
    int tx = threadIdx.x & 31, ty = threadIdx.x >> 5;
#pragma unroll
    for (int i = 0; i < 32; i += 8)
        t[ty + i][tx] = src[(size_t)(r0 + ty + i) * ld_src + c0 + tx];
    __syncthreads();
#pragma unroll
    for (int i = 0; i < 32; i += 8)
        dst[(size_t)(c0 + ty + i) * ld_dst + r0 + tx] = t[tx][ty + i];
}

__global__ void k_rowsum(const float* __restrict__ A, float* __restrict__ r) {
    __shared__ float sm[4];
    const float4* p = (const float4*)(A + (size_t)blockIdx.x * 4096);
    float s = 0.f;
#pragma unroll
    for (int j = 0; j < 4; ++j) {
        float4 v = p[threadIdx.x + j * 256];
        s += v.x + v.y + v.z + v.w;
    }
#pragma unroll
    for (int o = 32; o; o >>= 1) s += __shfl_down(s, o, 64);
    if ((threadIdx.x & 63) == 0) sm[threadIdx.x >> 6] = s;
    __syncthreads();
    if (threadIdx.x == 0) r[blockIdx.x] = sm[0] + sm[1] + sm[2] + sm[3];
}

__global__ void k_colsum(const float* __restrict__ A, float* __restrict__ col) {
    int j = blockIdx.x * 256 + threadIdx.x;
    float s = 0.f;
    for (int i = 0; i < 4096; ++i) s += A[(size_t)i * 4096 + j];
    col[j] = s;
}

__global__ void k_bias_concat(const float* __restrict__ bq, const float* __restrict__ bk,
                              const float* __restrict__ bv, float* __restrict__ o) {
    int i = blockIdx.x * 256 + threadIdx.x;
    o[i] = i < 1024 ? bq[i] : (i < 2048 ? bk[i - 1024] : bv[i - 2048]);
}

__global__ void k_layernorm(const float* __restrict__ wx, const float* __restrict__ gamma,
                            const float* __restrict__ beta, u16* __restrict__ h) {
    __shared__ float sm[8];
    size_t base = (size_t)blockIdx.x * 1024;
    float4 v = ((const float4*)(wx + base))[threadIdx.x];
    float s = v.x + v.y + v.z + v.w;
    float q = v.x * v.x + v.y * v.y + v.z * v.z + v.w * v.w;
#pragma unroll
    for (int o = 32; o; o >>= 1) { s += __shfl_down(s, o, 64); q += __shfl_down(q, o, 64); }
    int lane = threadIdx.x & 63, w = threadIdx.x >> 6;
    if (lane == 0) { sm[w] = s; sm[4 + w] = q; }
    __syncthreads();
    s = sm[0] + sm[1] + sm[2] + sm[3];
    q = sm[4] + sm[5] + sm[6] + sm[7];
    float mu = s * (1.f / 1024.f);
    float var = q * (1.f / 1024.f) - mu * mu;
    float rstd = rsqrtf(var + 1e-5f);
    int c = threadIdx.x * 4;
    ushort4 o;
    o.x = f2bf((v.x - mu) * rstd * gamma[c + 0] + beta[c + 0]);
    o.y = f2bf((v.y - mu) * rstd * gamma[c + 1] + beta[c + 1]);
    o.z = f2bf((v.z - mu) * rstd * gamma[c + 2] + beta[c + 2]);
    o.w = f2bf((v.w - mu) * rstd * gamma[c + 3] + beta[c + 3]);
    *(ushort4*)(h + base + c) = o;
}

__global__ void k_softmax(const float* __restrict__ S, u16* __restrict__ P) {
    __shared__ float sm[8];
    size_t base = (size_t)blockIdx.x * 4096;
    const float4* p = (const float4*)(S + base);
    float4 v[4];
#pragma unroll
    for (int j = 0; j < 4; ++j) v[j] = p[threadIdx.x + j * 256];
    float m = -3.4e38f;
#pragma unroll
    for (int j = 0; j < 4; ++j)
        m = fmaxf(m, fmaxf(fmaxf(v[j].x, v[j].y), fmaxf(v[j].z, v[j].w)));
#pragma unroll
    for (int o = 32; o; o >>= 1) m = fmaxf(m, __shfl_down(m, o, 64));
    int lane = threadIdx.x & 63, w = threadIdx.x >> 6;
    if (lane == 0) sm[w] = m;
    __syncthreads();
    m = fmaxf(fmaxf(sm[0], sm[1]), fmaxf(sm[2], sm[3]));
    float s = 0.f;
#pragma unroll
    for (int j = 0; j < 4; ++j) {
        v[j].x = __expf(v[j].x - m); v[j].y = __expf(v[j].y - m);
        v[j].z = __expf(v[j].z - m); v[j].w = __expf(v[j].w - m);
        s += v[j].x + v[j].y + v[j].z + v[j].w;
    }
#pragma unroll
    for (int o = 32; o; o >>= 1) s += __shfl_down(s, o, 64);
    if (lane == 0) sm[4 + w] = s;
    __syncthreads();
    s = sm[4] + sm[5] + sm[6] + sm[7];
    float inv = 1.f / s;
#pragma unroll
    for (int j = 0; j < 4; ++j) {
        ushort4 o;
        o.x = f2bf(v[j].x * inv); o.y = f2bf(v[j].y * inv);
        o.z = f2bf(v[j].z * inv); o.w = f2bf(v[j].w * inv);
        *(ushort4*)(P + base + (size_t)(threadIdx.x + j * 256) * 4) = o;
    }
}

// ---------------- the GEMM: C[M,N] = A[M,K] @ B[K,N], B given transposed [N,K] ----------------
// 128x128 tile, BK=32, 4 waves of 4x4 mfma_f32_16x16x32_bf16 (m97 structure).

#define EPI_M_BUILD 0
#define EPI_F32     1
#define EPI_WEIGHTED 2
#define EPI_QKV     3
#define EPI_SCORES  4
#define EPI_BF16    5
#define EPI_FINAL   6

template <int EPI>
__launch_bounds__(256, 2)
__global__ void gemm_bt(const u16* __restrict__ A, const u16* __restrict__ Bt,
                        int K, int lda, int ldb, int ldc,
                        void* __restrict__ Cout,
                        const float* __restrict__ e0, const float* __restrict__ e1,
                        const float* __restrict__ e2, const float* __restrict__ e3,
                        float scale, int kidx) {
    __shared__ __align__(16) u16 As[128 * 32];
    __shared__ __align__(16) u16 Bs[128 * 32];
    const int tid = threadIdx.x;
    const int m0 = blockIdx.y * 128, n0 = blockIdx.x * 128;
    const int lane = tid & 63, wave = tid >> 6;
    const int wm = (wave >> 1) * 64, wn = (wave & 1) * 64;
    const int fr = lane & 15, quad = lane >> 4;

    f32x4 acc[4][4] = {};

    // staging: 512 16B chunks per tile; chunk c -> row c>>2, k-part (c&3)*8
    const int ar = tid >> 2, ak = (tid & 3) * 8;
    const u16* gA0 = A + (size_t)(m0 + ar) * lda + ak;
    const u16* gA1 = gA0 + (size_t)64 * lda;
    const u16* gB0 = Bt + (size_t)(n0 + ar) * ldb + ak;
    const u16* gB1 = gB0 + (size_t)64 * ldb;
    u16* lA0 = As + tid * 8;
    u16* lA1 = As + (tid + 256) * 8;
    u16* lB0 = Bs + tid * 8;
    u16* lB1 = Bs + (tid + 256) * 8;

    for (int kk = 0; kk < K; kk += 32) {
        __syncthreads();                 // protect LDS from previous iteration's readers
        gld_lds16(gA0 + kk, lA0);
        gld_lds16(gA1 + kk, lA1);
        gld_lds16(gB0 + kk, lB0);
        gld_lds16(gB1 + kk, lB1);
        __syncthreads();                 // drains vmcnt before barrier

        bf16x8 af[4], bfv[4];
#pragma unroll
        for (int i = 0; i < 4; ++i)
            af[i] = *(const bf16x8*)(As + (wm + i * 16 + fr) * 32 + quad * 8);
#pragma unroll
        for (int i = 0; i < 4; ++i)
            bfv[i] = *(const bf16x8*)(Bs + (wn + i * 16 + fr) * 32 + quad * 8);
#pragma unroll
        for (int mi = 0; mi < 4; ++mi)
#pragma unroll
            for (int ni = 0; ni < 4; ++ni)
                acc[mi][ni] = __builtin_amdgcn_mfma_f32_16x16x32_bf16(af[mi], bfv[ni], acc[mi][ni], 0, 0, 0);
    }

    // epilogue: C/D layout col = lane&15, row = quad*4 + reg
#pragma unroll
    for (int mi = 0; mi < 4; ++mi) {
#pragma unroll
        for (int r = 0; r < 4; ++r) {
            int row = m0 + wm + mi * 16 + quad * 4 + r;
#pragma unroll
            for (int ni = 0; ni < 4; ++ni) {
                int col = n0 + wn + ni * 16 + fr;
                float v = acc[mi][ni][r];
                size_t ci = (size_t)row * ldc + col;
                if constexpr (EPI == EPI_M_BUILD) {
                    size_t gi = (size_t)row * 4096 + col;
                    float denom = e2[row] + e3[col] - v + 1e-6f;
                    ((u16*)Cout)[ci] = f2bf(e0[gi] + v / denom + e1[gi]);
                } else if constexpr (EPI == EPI_F32) {
                    ((float*)Cout)[ci] = v;
                } else if constexpr (EPI == EPI_WEIGHTED) {
                    float w = e0[(size_t)row * 10 + kidx];
                    float add = w * (v + e1[(size_t)kidx * 1024 + col]);
                    float* C = (float*)Cout;
                    if (kidx == 0) C[ci] = add; else C[ci] += add;
                } else if constexpr (EPI == EPI_QKV) {
                    ((u16*)Cout)[ci] = f2bf(v + e0[col]);
                } else if constexpr (EPI == EPI_SCORES) {
                    ((float*)Cout)[ci] = v * scale + e0[(size_t)row * 4096 + col];
                } else if constexpr (EPI == EPI_BF16) {
                    ((u16*)Cout)[ci] = f2bf(v);
                } else { // EPI_FINAL
                    float y = v + e0[col] + e1[(size_t)row * 4096 + col];
                    ((float*)Cout)[ci] = y > 0.f ? y : 0.f;
                }
            }
        }
    }
}

// ---------------- launch ----------------

extern "C" void kernel_launch(void* const* d_in, const int* in_sizes, int n_in,
                              void* d_out, int out_size, void* d_ws, size_t ws_size,
                              hipStream_t stream) {
    (void)in_sizes; (void)n_in; (void)out_size; (void)ws_size;
    const float* x   = (const float*)d_in[0];
    const float* A   = (const float*)d_in[1];
    const float* gm  = (const float*)d_in[2];
    const float* wts = (const float*)d_in[3];
    const float* Wst = (const float*)d_in[4];
    const float* bst = (const float*)d_in[5];
    const float* Wq  = (const float*)d_in[6];
    const float* bq  = (const float*)d_in[7];
    const float* Wk  = (const float*)d_in[8];
    const float* bk  = (const float*)d_in[9];
    const float* Wv  = (const float*)d_in[10];
    const float* bv  = (const float*)d_in[11];
    const float* Wo  = (const float*)d_in[12];
    const float* bo  = (const float*)d_in[13];
    const float* gamma = (const float*)d_in[14];
    const float* beta  = (const float*)d_in[15];
    float* out = (float*)d_out;
    char* ws = (char*)d_ws;

    const int N = 4096, DM = 1024;
    const size_t MB32 = 33554432UL;
    // arena (lifetime-overlapped), total ~248 MB:
    u16*   A_bf   = (u16*)(ws + 0);               // dead after inter GEMM
    u16*   A_bfT  = (u16*)(ws + MB32);            // dead after inter GEMM
    float* scores = (float*)(ws + 0);             // written phase 7
    u16*   x_bfT  = (u16*)(ws + 2 * MB32);        // dead after dng GEMM
    u16*   attn   = (u16*)(ws + 2 * MB32);        // written phase 8
    u16*   x_bf   = (u16*)(ws + 3 * MB32);        // dead after weighted loop
    u16*   WqkvT  = (u16*)(ws + 3 * MB32);        // written after weighted loop
    float* bqkv   = (float*)(ws + 3 * MB32 + 6291456UL);
    u16*   QKV    = (u16*)(ws + 3 * MB32 + 6307840UL);
    u16*   M_bf   = (u16*)(ws + 4 * MB32);        // dead after dng GEMM
    u16*   WkT    = (u16*)(ws + 4 * MB32);        // per-k, weighted loop
    u16*   V_T    = (u16*)(ws + 4 * MB32);        // written phase 6
    u16*   WoT    = (u16*)(ws + 4 * MB32 + 8388608UL);
    u16*   out_bf = (u16*)(ws + 4 * MB32 + 16777216UL);
    float* dng    = (float*)(ws + 5 * MB32);      // 67 MB, lives to end
    float* wxf    = (float*)(ws + 5 * MB32 + 67108864UL);
    u16*   h_bf   = (u16*)(ws + 5 * MB32 + 83886080UL);
    float* rowS   = (float*)(ws + 5 * MB32 + 92274688UL);
    float* colS   = (float*)(ws + 5 * MB32 + 92291072UL);

    // phase 0: conversions + degree sums
    k_convert_bf16<<<16384, 256, 0, stream>>>(A, A_bf, (long)N * N);
    k_transpose_f32_bf16<<<dim3(128, 128), 256, 0, stream>>>(A, A_bfT, N, N, N, N);
    k_convert_bf16<<<16384, 256, 0, stream>>>(x, x_bf, (long)N * N);
    k_transpose_f32_bf16<<<dim3(128, 128), 256, 0, stream>>>(x, x_bfT, N, N, N, N);
    k_rowsum<<<N, 256, 0, stream>>>(A, rowS);
    k_colsum<<<16, 256, 0, stream>>>(A, colS);

    // phase 1: inter = A@A, epilogue builds M = A + sim + gm (bf16)
    gemm_bt<EPI_M_BUILD><<<dim3(32, 32), 256, 0, stream>>>(
        A_bf, A_bfT, N, N, N, N, M_bf, A, gm, rowS, colS, 0.f, 0);

    // phase 2: dng = M @ x (fp32)
    gemm_bt<EPI_F32><<<dim3(32, 32), 256, 0, stream>>>(
        M_bf, x_bfT, N, N, N, N, dng, nullptr, nullptr, nullptr, nullptr, 0.f, 0);

    // phase 3: weighted_x = sum_k w[:,k] * (x @ W_k + b_k)
    for (int k = 0; k < 10; ++k) {
        k_transpose_f32_bf16<<<dim3(32, 128), 256, 0, stream>>>(
            Wst + (size_t)k * N * DM, WkT, N, DM, DM, N);
        gemm_bt<EPI_WEIGHTED><<<dim3(8, 32), 256, 0, stream>>>(
            x_bf, WkT, N, N, N, DM, wxf, wts, bst, nullptr, nullptr, 0.f, k);
    }

    // phase 4: QKV weight prep + layernorm
    k_transpose_f32_bf16<<<dim3(32, 32), 256, 0, stream>>>(Wq, WqkvT, DM, DM, DM, DM);
    k_transpose_f32_bf16<<<dim3(32, 32), 256, 0, stream>>>(Wk, WqkvT + (size_t)DM * DM, DM, DM, DM, DM);
    k_transpose_f32_bf16<<<dim3(32, 32), 256, 0, stream>>>(Wv, WqkvT + 2 * (size_t)DM * DM, DM, DM, DM, DM);
    k_bias_concat<<<12, 256, 0, stream>>>(bq, bk, bv, bqkv);
    k_layernorm<<<N, 256, 0, stream>>>(wxf, gamma, beta, h_bf);

    // phase 5: QKV = h @ [Wq|Wk|Wv] + bias  (bf16, ldc=3072)
    gemm_bt<EPI_QKV><<<dim3(24, 32), 256, 0, stream>>>(
        h_bf, WqkvT, DM, DM, DM, 3072, QKV, bqkv, nullptr, nullptr, nullptr, 0.f, 0);

    // phase 6: V^T
    k_transpose_u16<<<dim3(32, 128), 256, 0, stream>>>(QKV + 2048, V_T, N, DM, 3072, N);

    // phase 7: scores = Q@K^T/32 + dng (fp32)
    gemm_bt<EPI_SCORES><<<dim3(32, 32), 256, 0, stream>>>(
        QKV, QKV + 1024, DM, 3072, 3072, N, scores, dng, nullptr, nullptr, nullptr, 0.03125f, 0);

    // phase 8: softmax rows -> attn (bf16)
    k_softmax<<<N, 256, 0, stream>>>(scores, attn);

    // phase 9: out = attn @ V (bf16)
    gemm_bt<EPI_BF16><<<dim3(8, 32), 256, 0, stream>>>(
        attn, V_T, N, N, N, DM, out_bf, nullptr, nullptr, nullptr, nullptr, 0.f, 0);

    // phase 10: y = relu(out @ Wo + bo + dng) -> d_out (fp32)
    k_transpose_f32_bf16<<<dim3(128, 32), 256, 0, stream>>>(Wo, WoT, DM, N, N, DM);
    gemm_bt<EPI_FINAL><<<dim3(32, 32), 256, 0, stream>>>(
        out_bf, WoT, DM, DM, DM, N, out, bo, dng, nullptr, nullptr, 0.f, 0);
}

// Round 3
// 1513.154 us; speedup vs baseline: 1.4030x; 1.4030x over previous
//
#include <hip/hip_runtime.h>
#include <hip/hip_bf16.h>

typedef unsigned short u16;
typedef __bf16 bf16x8 __attribute__((ext_vector_type(8)));
typedef float f32x4 __attribute__((ext_vector_type(4)));

__device__ __forceinline__ u16 f2bf(float v) {
    __hip_bfloat16 h = __float2bfloat16(v);
    return __builtin_bit_cast(u16, h);
}
__device__ __forceinline__ float bf2f(u16 v) {
    __hip_bfloat16 h = __builtin_bit_cast(__hip_bfloat16, v);
    return __bfloat162float(h);
}

// async global -> LDS, 16B per lane. LDS dst must be wave-uniform-base + lane*16.
__device__ __forceinline__ void gld_lds16(const u16* g, u16* l) {
    __builtin_amdgcn_global_load_lds(
        (const __attribute__((address_space(1))) unsigned int*)(const void*)g,
        (__attribute__((address_space(3))) unsigned int*)(void*)l, 16, 0, 0);
}

// ---------------- elementwise / transform kernels ----------------

__global__ void k_convert_bf16(const float* __restrict__ s, u16* __restrict__ d, long n) {
    long i = ((long)blockIdx.x * 256 + threadIdx.x) * 4;
    if (i < n) {
        float4 v = *(const float4*)(s + i);
        u16 a = f2bf(v.x), b = f2bf(v.y), c = f2bf(v.z), e = f2bf(v.w);
        ushort4 o; o.x = a; o.y = b; o.z = c; o.w = e;
        *(ushort4*)(d + i) = o;
    }
}

__global__ void k_zero_f32(float* __restrict__ p) {
    float4 z; z.x = z.y = z.z = z.w = 0.f;
    ((float4*)p)[(size_t)blockIdx.x * 256 + threadIdx.x] = z;
}

// dst[c][r] = bf16(src[r][c]); grid (C/32, R/32), block 256
__global__ void k_transpose_f32_bf16(const float* __restrict__ src, u16* __restrict__ dst,
                                     int R, int C, int ld_src, int ld_dst) {
    __shared__ u16 t[32][33];
    int c0 = blockIdx.x * 32, r0 = blockIdx.y * 32;
    int tx = threadIdx.x & 31, ty = threadIdx.x >> 5; // ty 0..7
#pragma unroll
    for (int i = 0; i < 32; i += 8)
        t[ty + i][tx] = f2bf(src[(size_t)(r0 + ty + i) * ld_src + c0 + tx]);
    __syncthreads();
#pragma unroll
    for (int i = 0; i < 32; i += 8)
        dst[(size_t)(c0 + ty + i) * ld_dst + r0 + tx] = t[tx][ty + i];
}

__global__ void k_transpose_u16(const u16* __restrict__ src, u16* __restrict__ dst,
                                int R, int C, int ld_src, int ld_dst) {
    __shared__ u16 t[32][33];
    int c0 = blockIdx.x * 32, r0 = blockIdx.y * 32;
    int tx = threadIdx.x & 31, ty = threadIdx.x >> 5;
#pragma unroll
    for (int i = 0; i < 32; i += 8)
        t[ty + i][tx] = src[(size_t)(r0 + ty + i) * ld_src + c0 + tx];
    __syncthreads();
#pragma unroll
    for (int i = 0; i < 32; i += 8)
        dst[(size_t)(c0 + ty + i) * ld_dst + r0 + tx] = t[tx][ty + i];
}

__global__ void k_rowsum(const float* __restrict__ A, float* __restrict__ r) {
    __shared__ float sm[4];
    const float4* p = (const float4*)(A + (size_t)blockIdx.x * 4096);
    float s = 0.f;
#pragma unroll
    for (int j = 0; j < 4; ++j) {
        float4 v = p[threadIdx.x + j * 256];
        s += v.x + v.y + v.z + v.w;
    }
#pragma unroll
    for (int o = 32; o; o >>= 1) s += __shfl_down(s, o, 64);
    if ((threadIdx.x & 63) == 0) sm[threadIdx.x >> 6] = s;
    __syncthreads();
    if (threadIdx.x == 0) r[blockIdx.x] = sm[0] + sm[1] + sm[2] + sm[3];
}

// row sums of bf16 [4096,4096]; applied to A^T -> column sums of A (0/1 exact in bf16)
__global__ void k_rowsum_bf16(const u16* __restrict__ A, float* __restrict__ r) {
    __shared__ float sm[4];
    const ushort4* p = (const ushort4*)(A + (size_t)blockIdx.x * 4096);
    float s = 0.f;
#pragma unroll
    for (int j = 0; j < 4; ++j) {
        ushort4 v = p[threadIdx.x + j * 256];
        s += bf2f(v.x) + bf2f(v.y) + bf2f(v.z) + bf2f(v.w);
    }
#pragma unroll
    for (int o = 32; o; o >>= 1) s += __shfl_down(s, o, 64);
    if ((threadIdx.x & 63) == 0) sm[threadIdx.x >> 6] = s;
    __syncthreads();
    if (threadIdx.x == 0) r[blockIdx.x] = sm[0] + sm[1] + sm[2] + sm[3];
}

__global__ void k_bias_concat(const float* __restrict__ bq, const float* __restrict__ bk,
                              const float* __restrict__ bv, float* __restrict__ o) {
    int i = blockIdx.x * 256 + threadIdx.x;
    o[i] = i < 1024 ? bq[i] : (i < 2048 ? bk[i - 1024] : bv[i - 2048]);
}

__global__ void k_layernorm(const float* __restrict__ wx, const float* __restrict__ gamma,
                            const float* __restrict__ beta, u16* __restrict__ h) {
    __shared__ float sm[8];
    size_t base = (size_t)blockIdx.x * 1024;
    float4 v = ((const float4*)(wx + base))[threadIdx.x];
    float s = v.x + v.y + v.z + v.w;
    float q = v.x * v.x + v.y * v.y + v.z * v.z + v.w * v.w;
#pragma unroll
    for (int o = 32; o; o >>= 1) { s += __shfl_down(s, o, 64); q += __shfl_down(q, o, 64); }
    int lane = threadIdx.x & 63, w = threadIdx.x >> 6;
    if (lane == 0) { sm[w] = s; sm[4 + w] = q; }
    __syncthreads();
    s = sm[0] + sm[1] + sm[2] + sm[3];
    q = sm[4] + sm[5] + sm[6] + sm[7];
    float mu = s * (1.f / 1024.f);
    float var = q * (1.f / 1024.f) - mu * mu;
    float rstd = rsqrtf(var + 1e-5f);
    int c = threadIdx.x * 4;
    ushort4 o;
    o.x = f2bf((v.x - mu) * rstd * gamma[c + 0] + beta[c + 0]);
    o.y = f2bf((v.y - mu) * rstd * gamma[c + 1] + beta[c + 1]);
    o.z = f2bf((v.z - mu) * rstd * gamma[c + 2] + beta[c + 2]);
    o.w = f2bf((v.w - mu) * rstd * gamma[c + 3] + beta[c + 3]);
    *(ushort4*)(h + base + c) = o;
}

__global__ void k_softmax(const float* __restrict__ S, u16* __restrict__ P) {
    __shared__ float sm[8];
    size_t base = (size_t)blockIdx.x * 4096;
    const float4* p = (const float4*)(S + base);
    float4 v[4];
#pragma unroll
    for (int j = 0; j < 4; ++j) v[j] = p[threadIdx.x + j * 256];
    float m = -3.4e38f;
#pragma unroll
    for (int j = 0; j < 4; ++j)
        m = fmaxf(m, fmaxf(fmaxf(v[j].x, v[j].y), fmaxf(v[j].z, v[j].w)));
#pragma unroll
    for (int o = 32; o; o >>= 1) m = fmaxf(m, __shfl_down(m, o, 64));
    int lane = threadIdx.x & 63, w = threadIdx.x >> 6;
    if (lane == 0) sm[w] = m;
    __syncthreads();
    m = fmaxf(fmaxf(sm[0], sm[1]), fmaxf(sm[2], sm[3]));
    float s = 0.f;
#pragma unroll
    for (int j = 0; j < 4; ++j) {
        v[j].x = __expf(v[j].x - m); v[j].y = __expf(v[j].y - m);
        v[j].z = __expf(v[j].z - m); v[j].w = __expf(v[j].w - m);
        s += v[j].x + v[j].y + v[j].z + v[j].w;
    }
#pragma unroll
    for (int o = 32; o; o >>= 1) s += __shfl_down(s, o, 64);
    if (lane == 0) sm[4 + w] = s;
    __syncthreads();
    s = sm[4] + sm[5] + sm[6] + sm[7];
    float inv = 1.f / s;
#pragma unroll
    for (int j = 0; j < 4; ++j) {
        ushort4 o;
        o.x = f2bf(v[j].x * inv); o.y = f2bf(v[j].y * inv);
        o.z = f2bf(v[j].z * inv); o.w = f2bf(v[j].w * inv);
        *(ushort4*)(P + base + (size_t)(threadIdx.x + j * 256) * 4) = o;
    }
}

// ---------------- the GEMM: C[M,N] = A[M,K] @ B[K,N], B given transposed [N,K] ----------------
// 128x128 tile, BK=32, 4 waves of 4x4 mfma_f32_16x16x32_bf16 (m97 structure).
// zb: per-blockIdx.z element stride added to Bt (z-batched B operand; 0 = unbatched).

#define EPI_M_BUILD 0
#define EPI_F32     1
#define EPI_WEIGHTED 2
#define EPI_QKV     3
#define EPI_SCORES  4
#define EPI_BF16    5
#define EPI_FINAL   6

template <int EPI>
__launch_bounds__(256, 2)
__global__ void gemm_bt(const u16* __restrict__ A, const u16* __restrict__ Bt,
                        int K, int lda, int ldb, int ldc,
                        void* __restrict__ Cout,
                        const float* __restrict__ e0, const float* __restrict__ e1,
                        const float* __restrict__ e2, const float* __restrict__ e3,
                        float scale, int kidx, size_t zb) {
    __shared__ __align__(16) u16 As[128 * 32];
    __shared__ __align__(16) u16 Bs[128 * 32];
    const int tid = threadIdx.x;
    const int m0 = blockIdx.y * 128, n0 = blockIdx.x * 128;
    const int lane = tid & 63, wave = tid >> 6;
    const int wm = (wave >> 1) * 64, wn = (wave & 1) * 64;
    const int fr = lane & 15, quad = lane >> 4;

    Bt += (size_t)blockIdx.z * zb;

    f32x4 acc[4][4] = {};

    // staging: 512 16B chunks per tile; chunk c -> row c>>2, k-part (c&3)*8
    const int ar = tid >> 2, ak = (tid & 3) * 8;
    const u16* gA0 = A + (size_t)(m0 + ar) * lda + ak;
    const u16* gA1 = gA0 + (size_t)64 * lda;
    const u16* gB0 = Bt + (size_t)(n0 + ar) * ldb + ak;
    const u16* gB1 = gB0 + (size_t)64 * ldb;
    u16* lA0 = As + tid * 8;
    u16* lA1 = As + (tid + 256) * 8;
    u16* lB0 = Bs + tid * 8;
    u16* lB1 = Bs + (tid + 256) * 8;

    for (int kk = 0; kk < K; kk += 32) {
        __syncthreads();                 // protect LDS from previous iteration's readers
        gld_lds16(gA0 + kk, lA0);
        gld_lds16(gA1 + kk, lA1);
        gld_lds16(gB0 + kk, lB0);
        gld_lds16(gB1 + kk, lB1);
        __syncthreads();                 // drains vmcnt before barrier

        bf16x8 af[4], bfv[4];
#pragma unroll
        for (int i = 0; i < 4; ++i)
            af[i] = *(const bf16x8*)(As + (wm + i * 16 + fr) * 32 + quad * 8);
#pragma unroll
        for (int i = 0; i < 4; ++i)
            bfv[i] = *(const bf16x8*)(Bs + (wn + i * 16 + fr) * 32 + quad * 8);
#pragma unroll
        for (int mi = 0; mi < 4; ++mi)
#pragma unroll
            for (int ni = 0; ni < 4; ++ni)
                acc[mi][ni] = __builtin_amdgcn_mfma_f32_16x16x32_bf16(af[mi], bfv[ni], acc[mi][ni], 0, 0, 0);
    }

    // epilogue: C/D layout col = lane&15, row = quad*4 + reg
#pragma unroll
    for (int mi = 0; mi < 4; ++mi) {
#pragma unroll
        for (int r = 0; r < 4; ++r) {
            int row = m0 + wm + mi * 16 + quad * 4 + r;
#pragma unroll
            for (int ni = 0; ni < 4; ++ni) {
                int col = n0 + wn + ni * 16 + fr;
                float v = acc[mi][ni][r];
                size_t ci = (size_t)row * ldc + col;
                if constexpr (EPI == EPI_M_BUILD) {
                    size_t gi = (size_t)row * 4096 + col;
                    float denom = e2[row] + e3[col] - v + 1e-6f;
                    ((u16*)Cout)[ci] = f2bf(e0[gi] + v / denom + e1[gi]);
                } else if constexpr (EPI == EPI_F32) {
                    ((float*)Cout)[ci] = v;
                } else if constexpr (EPI == EPI_WEIGHTED) {
                    // z-batched over k: atomic accumulate w_k(row) * ((x@W_k)[row,col] + b_k[col])
                    float w = e0[(size_t)row * 10 + blockIdx.z];
                    atomicAdd((float*)Cout + ci,
                              w * (v + e1[(size_t)blockIdx.z * 1024 + col]));
                } else if constexpr (EPI == EPI_QKV) {
                    ((u16*)Cout)[ci] = f2bf(v + e0[col]);
                } else if constexpr (EPI == EPI_SCORES) {
                    ((float*)Cout)[ci] = v * scale + e0[(size_t)row * 4096 + col];
                } else if constexpr (EPI == EPI_BF16) {
                    ((u16*)Cout)[ci] = f2bf(v);
                } else { // EPI_FINAL
                    float y = v + e0[col] + e1[(size_t)row * 4096 + col];
                    ((float*)Cout)[ci] = y > 0.f ? y : 0.f;
                }
            }
        }
    }
}

// ---------------- launch ----------------

extern "C" void kernel_launch(void* const* d_in, const int* in_sizes, int n_in,
                              void* d_out, int out_size, void* d_ws, size_t ws_size,
                              hipStream_t stream) {
    (void)in_sizes; (void)n_in; (void)out_size; (void)ws_size;
    const float* x   = (const float*)d_in[0];
    const float* A   = (const float*)d_in[1];
    const float* gm  = (const float*)d_in[2];
    const float* wts = (const float*)d_in[3];
    const float* Wst = (const float*)d_in[4];
    const float* bst = (const float*)d_in[5];
    const float* Wq  = (const float*)d_in[6];
    const float* bq  = (const float*)d_in[7];
    const float* Wk  = (const float*)d_in[8];
    const float* bk  = (const float*)d_in[9];
    const float* Wv  = (const float*)d_in[10];
    const float* bv  = (const float*)d_in[11];
    const float* Wo  = (const float*)d_in[12];
    const float* bo  = (const float*)d_in[13];
    const float* gamma = (const float*)d_in[14];
    const float* beta  = (const float*)d_in[15];
    float* out = (float*)d_out;
    char* ws = (char*)d_ws;

    const int N = 4096, DM = 1024;
    const size_t MB32 = 33554432UL;
    // round-1 arena (proven), plus WallT at [0,80 MB) for phase 3
    u16*   A_bf   = (u16*)(ws + 0);               // dead after inter GEMM
    u16*   A_bfT  = (u16*)(ws + MB32);            // dead after inter GEMM
    float* scores = (float*)(ws + 0);             // written phase 7
    u16*   x_bfT  = (u16*)(ws + 2 * MB32);        // dead after dng GEMM
    u16*   attn   = (u16*)(ws + 2 * MB32);        // written phase 8
    u16*   x_bf   = (u16*)(ws + 3 * MB32);        // dead after weighted GEMM
    u16*   WqkvT  = (u16*)(ws + 3 * MB32);        // written phase 4
    float* bqkv   = (float*)(ws + 3 * MB32 + 6291456UL);
    u16*   QKV    = (u16*)(ws + 3 * MB32 + 6307840UL);
    u16*   M_bf   = (u16*)(ws + 4 * MB32);        // dead after dng GEMM
    u16*   WallT  = (u16*)(ws + 0);               // [0,80MB) phase 3 (A_bf/A_bfT/x_bfT dead)
    u16*   V_T    = (u16*)(ws + 4 * MB32);        // written phase 6
    u16*   WoT    = (u16*)(ws + 4 * MB32 + 8388608UL);
    u16*   out_bf = (u16*)(ws + 4 * MB32 + 16777216UL);
    float* dng    = (float*)(ws + 5 * MB32);      // 64 MB, lives to end
    float* wxf    = (float*)(ws + 5 * MB32 + 67108864UL);
    u16*   h_bf   = (u16*)(ws + 5 * MB32 + 83886080UL);
    float* rowS   = (float*)(ws + 5 * MB32 + 92274688UL);
    float* colS   = (float*)(ws + 5 * MB32 + 92291072UL);

    // phase 0: conversions + degree sums
    k_convert_bf16<<<16384, 256, 0, stream>>>(A, A_bf, (long)N * N);
    k_transpose_f32_bf16<<<dim3(128, 128), 256, 0, stream>>>(A, A_bfT, N, N, N, N);
    k_convert_bf16<<<16384, 256, 0, stream>>>(x, x_bf, (long)N * N);
    k_transpose_f32_bf16<<<dim3(128, 128), 256, 0, stream>>>(x, x_bfT, N, N, N, N);
    k_rowsum<<<N, 256, 0, stream>>>(A, rowS);
    k_rowsum_bf16<<<N, 256, 0, stream>>>(A_bfT, colS);   // column sums of A via A^T row sums

    // phase 1: inter = A@A, epilogue builds M = A + sim + gm (bf16)
    gemm_bt<EPI_M_BUILD><<<dim3(32, 32), 256, 0, stream>>>(
        A_bf, A_bfT, N, N, N, N, M_bf, A, gm, rowS, colS, 0.f, 0, 0);

    // phase 2: dng = M @ x (fp32)
    gemm_bt<EPI_F32><<<dim3(32, 32), 256, 0, stream>>>(
        M_bf, x_bfT, N, N, N, N, dng, nullptr, nullptr, nullptr, nullptr, 0.f, 0, 0);

    // phase 3: weighted_x = sum_k w[:,k]*(x@W_k + b_k)
    // 10 per-k transposes into one 80MB slab, then ONE z-batched GEMM (2560 blocks)
    // with atomic accumulation into zeroed wxf.
    for (int k = 0; k < 10; ++k)
        k_transpose_f32_bf16<<<dim3(32, 128), 256, 0, stream>>>(
            Wst + (size_t)k * N * DM, WallT + (size_t)k * DM * N, N, DM, DM, N);
    k_zero_f32<<<4096, 256, 0, stream>>>(wxf);
    gemm_bt<EPI_WEIGHTED><<<dim3(8, 32, 10), 256, 0, stream>>>(
        x_bf, WallT, N, N, N, DM, wxf, wts, bst, nullptr, nullptr, 0.f, 0, (size_t)DM * N);

    // phase 4: QKV weight prep + layernorm
    k_transpose_f32_bf16<<<dim3(32, 32), 256, 0, stream>>>(Wq, WqkvT, DM, DM, DM, DM);
    k_transpose_f32_bf16<<<dim3(32, 32), 256, 0, stream>>>(Wk, WqkvT + (size_t)DM * DM, DM, DM, DM, DM);
    k_transpose_f32_bf16<<<dim3(32, 32), 256, 0, stream>>>(Wv, WqkvT + 2 * (size_t)DM * DM, DM, DM, DM, DM);
    k_bias_concat<<<12, 256, 0, stream>>>(bq, bk, bv, bqkv);
    k_layernorm<<<N, 256, 0, stream>>>(wxf, gamma, beta, h_bf);

    // phase 5: QKV = h @ [Wq|Wk|Wv] + bias  (bf16, ldc=3072)
    gemm_bt<EPI_QKV><<<dim3(24, 32), 256, 0, stream>>>(
        h_bf, WqkvT, DM, DM, DM, 3072, QKV, bqkv, nullptr, nullptr, nullptr, 0.f, 0, 0);

    // phase 6: V^T
    k_transpose_u16<<<dim3(32, 128), 256, 0, stream>>>(QKV + 2048, V_T, N, DM, 3072, N);

    // phase 7: scores = Q@K^T/32 + dng (fp32)
    gemm_bt<EPI_SCORES><<<dim3(32, 32), 256, 0, stream>>>(
        QKV, QKV + 1024, DM, 3072, 3072, N, scores, dng, nullptr, nullptr, nullptr, 0.03125f, 0, 0);

    // phase 8: softmax rows -> attn (bf16)
    k_softmax<<<N, 256, 0, stream>>>(scores, attn);

    // phase 9: out = attn @ V (bf16)
    gemm_bt<EPI_BF16><<<dim3(8, 32), 256, 0, stream>>>(
        attn, V_T, N, N, N, DM, out_bf, nullptr, nullptr, nullptr, nullptr, 0.f, 0, 0);

    // phase 10: y = relu(out @ Wo + bo + dng) -> d_out (fp32)
    k_transpose_f32_bf16<<<dim3(128, 32), 256, 0, stream>>>(Wo, WoT, DM, N, N, DM);
    gemm_bt<EPI_FINAL><<<dim3(32, 32), 256, 0, stream>>>(
        out_bf, WoT, DM, DM, DM, N, out, bo, dng, nullptr, nullptr, 0.f, 0, 0);
}